// Round 1
// baseline (199.758 us; speedup 1.0000x reference)
//
#include <hip/hip_runtime.h>
#include <hip/hip_bf16.h>
#include <stdint.h>

// Problem constants (CZT_72533407694901)
#define MM   1840          // M (zoom bins)
#define M2   3680          // 2M rows of W / X
#define NN   512           // N time samples
#define K2   1024          // 2N columns of W
#define CS   8192          // C*S = 32*256
#define MPAD 3712          // 29 * 128 (GEMM row padding)

typedef __bf16 bf16x8 __attribute__((ext_vector_type(8)));
typedef float  floatx4 __attribute__((ext_vector_type(4)));

// -------------------------------------------------------------------------
// Kernel 1: assemble W output = [[Wr, -Wi],[Wi, Wr]], clamp [-1,1] (no-op).
// One block per row j (3680), one thread per float4 (256 * 4 = 1024 cols).
// -------------------------------------------------------------------------
__global__ __launch_bounds__(256) void czt_wout(const float* __restrict__ Wr,
                                                const float* __restrict__ Wi,
                                                float* __restrict__ Wout) {
    const int j  = blockIdx.x;           // 0..3679
    const int c4 = threadIdx.x * 4;      // 0..1020
    const int jj = (j < MM) ? j : j - MM;
    const bool top = (j < MM);
    const bool first = (c4 < NN);
    const int col = first ? c4 : c4 - NN;

    float4 v;
    if (top) {
        if (first) {
            v = *(const float4*)&Wr[(size_t)jj * NN + col];
        } else {
            v = *(const float4*)&Wi[(size_t)jj * NN + col];
            v.x = -v.x; v.y = -v.y; v.z = -v.z; v.w = -v.w;
        }
    } else {
        if (first) v = *(const float4*)&Wi[(size_t)jj * NN + col];
        else       v = *(const float4*)&Wr[(size_t)jj * NN + col];
    }
    v.x = fminf(1.0f, fmaxf(-1.0f, v.x));
    v.y = fminf(1.0f, fmaxf(-1.0f, v.y));
    v.z = fminf(1.0f, fmaxf(-1.0f, v.z));
    v.w = fminf(1.0f, fmaxf(-1.0f, v.w));
    *(float4*)&Wout[(size_t)j * K2 + c4] = v;
}

// -------------------------------------------------------------------------
// Kernel 2: A'' bf16 [MPAD x 512], K-contiguous.
//   j < M :  Wr*ac - Wi*as   (= cos(w+a))
//   j >= M:  Wi*ac + Wr*as   (= sin(w+a))
// Rows 3680..3711 zero-padded (ws is poisoned 0xAA every call).
// -------------------------------------------------------------------------
__global__ __launch_bounds__(128) void czt_aprep(const float* __restrict__ Wr,
                                                 const float* __restrict__ Wi,
                                                 const float* __restrict__ ac,
                                                 const float* __restrict__ as_,
                                                 __hip_bfloat16* __restrict__ Abf) {
    const int j = blockIdx.x;          // 0..3711
    const int k = threadIdx.x * 4;     // 0..508

    union { __hip_bfloat16 h[4]; uint2 u; } p;
    if (j < M2) {
        const int jj = (j < MM) ? j : j - MM;
        const float4 wr = *(const float4*)&Wr[(size_t)jj * NN + k];
        const float4 wi = *(const float4*)&Wi[(size_t)jj * NN + k];
        const float4 c  = *(const float4*)&ac[k];
        const float4 s  = *(const float4*)&as_[k];
        float v0, v1, v2, v3;
        if (j < MM) {
            v0 = wr.x * c.x - wi.x * s.x;
            v1 = wr.y * c.y - wi.y * s.y;
            v2 = wr.z * c.z - wi.z * s.z;
            v3 = wr.w * c.w - wi.w * s.w;
        } else {
            v0 = wi.x * c.x + wr.x * s.x;
            v1 = wi.y * c.y + wr.y * s.y;
            v2 = wi.z * c.z + wr.z * s.z;
            v3 = wi.w * c.w + wr.w * s.w;
        }
        p.h[0] = __float2bfloat16(v0);
        p.h[1] = __float2bfloat16(v1);
        p.h[2] = __float2bfloat16(v2);
        p.h[3] = __float2bfloat16(v3);
    } else {
        p.h[0] = __float2bfloat16(0.0f);
        p.h[1] = __float2bfloat16(0.0f);
        p.h[2] = __float2bfloat16(0.0f);
        p.h[3] = __float2bfloat16(0.0f);
    }
    *(uint2*)&Abf[(size_t)j * NN + k] = p.u;
}

// -------------------------------------------------------------------------
// Kernel 3: transpose x [512 x 8192] fp32 -> Bxt bf16 [8192 x 512].
// Classic 32x32 LDS tile, +1 pad to kill bank conflicts.
// -------------------------------------------------------------------------
__global__ __launch_bounds__(256) void czt_xt(const float* __restrict__ x,
                                              __hip_bfloat16* __restrict__ Bxt) {
    __shared__ float tile[32][33];
    const int tx = threadIdx.x;            // 0..31
    const int ty = threadIdx.y;            // 0..7
    const int n0 = blockIdx.x * 32;        // over CS
    const int k0 = blockIdx.y * 32;        // over N

#pragma unroll
    for (int i = 0; i < 4; ++i) {
        const int k = k0 + ty + i * 8;
        tile[ty + i * 8][tx] = x[(size_t)k * CS + n0 + tx];
    }
    __syncthreads();
#pragma unroll
    for (int i = 0; i < 4; ++i) {
        const int n = n0 + ty + i * 8;
        Bxt[(size_t)n * NN + k0 + tx] = __float2bfloat16(tile[tx][ty + i * 8]);
    }
}

// -------------------------------------------------------------------------
// Kernel 4: GEMM  X[3680 x 8192] = A''[3680 x 512] * x[512 x 8192]
// Both operands K-contiguous bf16 (A: [m][k], B^T: [n][k]).
// 128x128 tile, BK=64, 256 threads (4 waves), each wave a 64x64 subtile
// (4x4 grid of 16x16x32 bf16 MFMA). global_load_lds width=16 staging.
// -------------------------------------------------------------------------
__device__ __forceinline__ void gload_lds16(const void* g, void* l) {
    __builtin_amdgcn_global_load_lds(
        (const __attribute__((address_space(1))) uint32_t*)g,
        (__attribute__((address_space(3))) uint32_t*)l,
        16, 0, 0);
}

__global__ __launch_bounds__(256) void czt_gemm(const __hip_bfloat16* __restrict__ Abf,
                                                const __hip_bfloat16* __restrict__ Bxt,
                                                float* __restrict__ Xout) {
    __shared__ __hip_bfloat16 As[128 * 64];   // [m in tile][k], stride 64
    __shared__ __hip_bfloat16 Bs[128 * 64];   // [n in tile][k], stride 64

    const int tid  = threadIdx.x;
    const int lane = tid & 63;
    const int w    = tid >> 6;        // wave 0..3
    const int quad = lane >> 4;       // 0..3
    const int r16  = lane & 15;

    const int mtile = blockIdx.y * 128;
    const int ntile = blockIdx.x * 128;
    const int wm = (w >> 1) * 64;     // wave row offset in tile
    const int wn = (w & 1) * 64;      // wave col offset in tile

    // Staging source addressing: wave w loads tile rows [w*32, w*32+32),
    // 4 issues of 8 rows x 64 elements (1024 B / wave-issue).
    const int rstage = w * 32 + (lane >> 3);   // row within tile
    const int cstage = (lane & 7) * 8;         // k element offset (16 B)
    const __hip_bfloat16* Ag = Abf + (size_t)(mtile + rstage) * NN + cstage;
    const __hip_bfloat16* Bg = Bxt + (size_t)(ntile + rstage) * NN + cstage;

    floatx4 acc[4][4] = {};

#pragma unroll 1
    for (int kt = 0; kt < NN / 64; ++kt) {
        __syncthreads();   // previous iter's LDS reads done before overwrite
#pragma unroll
        for (int t = 0; t < 4; ++t) {
            gload_lds16(Ag + (size_t)(t * 8) * NN + kt * 64, &As[(w * 32 + t * 8) * 64]);
            gload_lds16(Bg + (size_t)(t * 8) * NN + kt * 64, &Bs[(w * 32 + t * 8) * 64]);
        }
        __syncthreads();   // drains vmcnt(0) before barrier -> tiles visible

#pragma unroll
        for (int ks = 0; ks < 2; ++ks) {
            bf16x8 af[4], bfr[4];
#pragma unroll
            for (int i = 0; i < 4; ++i) {
                af[i]  = *(const bf16x8*)&As[(wm + i * 16 + r16) * 64 + ks * 32 + quad * 8];
                bfr[i] = *(const bf16x8*)&Bs[(wn + i * 16 + r16) * 64 + ks * 32 + quad * 8];
            }
#pragma unroll
            for (int i = 0; i < 4; ++i)
#pragma unroll
                for (int jn = 0; jn < 4; ++jn)
                    acc[i][jn] = __builtin_amdgcn_mfma_f32_16x16x32_bf16(
                        af[i], bfr[jn], acc[i][jn], 0, 0, 0);
        }
    }

    // Epilogue: C/D layout col = lane&15, row = quad*4 + reg.
#pragma unroll
    for (int i = 0; i < 4; ++i) {
        const int rbase = mtile + wm + i * 16 + quad * 4;
#pragma unroll
        for (int rr = 0; rr < 4; ++rr) {
            const int rg = rbase + rr;
            if (rg < M2) {
#pragma unroll
                for (int jn = 0; jn < 4; ++jn) {
                    const int cg = ntile + wn + jn * 16 + r16;
                    Xout[(size_t)rg * CS + cg] = acc[i][jn][rr];
                }
            }
        }
    }
}

// -------------------------------------------------------------------------
extern "C" void kernel_launch(void* const* d_in, const int* in_sizes, int n_in,
                              void* d_out, int out_size, void* d_ws, size_t ws_size,
                              hipStream_t stream) {
    const float* x   = (const float*)d_in[0];   // [512, 32, 256]
    const float* Wr  = (const float*)d_in[1];   // [1840, 512]
    const float* Wi  = (const float*)d_in[2];   // [1840, 512]
    const float* ac  = (const float*)d_in[3];   // [512]
    const float* as_ = (const float*)d_in[4];   // [512]

    float* Wout = (float*)d_out;                       // [3680, 1024]
    float* Xout = (float*)d_out + (size_t)M2 * K2;     // [3680, 8192]

    __hip_bfloat16* Abf = (__hip_bfloat16*)d_ws;                       // [3712, 512]
    __hip_bfloat16* Bxt = (__hip_bfloat16*)((char*)d_ws + (size_t)MPAD * NN * 2); // [8192, 512]

    czt_wout <<<dim3(M2),        dim3(256),     0, stream>>>(Wr, Wi, Wout);
    czt_aprep<<<dim3(MPAD),      dim3(128),     0, stream>>>(Wr, Wi, ac, as_, Abf);
    czt_xt   <<<dim3(CS / 32, NN / 32), dim3(32, 8), 0, stream>>>(x, Bxt);
    czt_gemm <<<dim3(CS / 128, MPAD / 128), dim3(256), 0, stream>>>(Abf, Bxt, Xout);
}

// Round 2
// 194.735 us; speedup vs baseline: 1.0258x; 1.0258x over previous
//
#include <hip/hip_runtime.h>
#include <hip/hip_bf16.h>
#include <stdint.h>

// Problem constants (CZT_72533407694901)
#define MM   1840          // M (zoom bins)
#define M2   3680          // 2M rows of W / X
#define NN   512           // N time samples
#define K2   1024          // 2N columns of W
#define CS   8192          // C*S = 32*256
#define MPAD 3712          // 29 * 128 (GEMM row padding)

#define WPREP_BLOCKS (MPAD / 2)        // 1856 blocks, 2 rows each
#define XT_NB        (CS / 32)         // 256 n-tiles
#define XT_KB        (NN / 64)         // 8 k-tiles

typedef __bf16 bf16x8 __attribute__((ext_vector_type(8)));
typedef float  floatx4 __attribute__((ext_vector_type(4)));

// -------------------------------------------------------------------------
// Kernel 1 (fused prep): block-index split between
//  (a) W-output assembly + A'' bf16 fold  (blocks [0, 1856))
//  (b) x transpose -> bf16 B^T            (blocks [1856, 1856+2048))
// Both halves are independent; fusing them into one grid lets them run
// concurrently and drops two kernel launches + tails.
// -------------------------------------------------------------------------
__global__ __launch_bounds__(256) void czt_prep(const float* __restrict__ Wr,
                                                const float* __restrict__ Wi,
                                                const float* __restrict__ ac,
                                                const float* __restrict__ as_,
                                                const float* __restrict__ x,
                                                float* __restrict__ Wout,
                                                __hip_bfloat16* __restrict__ Abf,
                                                __hip_bfloat16* __restrict__ Bxt) {
    __shared__ float tile[64 * 33];     // transpose staging (pad 33: <=2-way, free)
    const int b   = blockIdx.x;
    const int tid = threadIdx.x;

    if (b < WPREP_BLOCKS) {
        // ---- (a) Wout row assembly + A'' fold: rows j = 2b, 2b+1 ----
        const int j = b * 2 + (tid >> 7);     // two rows per 256-thread block
        const int k = (tid & 127) * 4;        // 0..508, float4 per thread

        union { __hip_bfloat16 h[4]; uint2 u; } p;
        if (j < M2) {
            const int jj = (j < MM) ? j : j - MM;
            const float4 wr = *(const float4*)&Wr[(size_t)jj * NN + k];
            const float4 wi = *(const float4*)&Wi[(size_t)jj * NN + k];
            const float4 c  = *(const float4*)&ac[k];
            const float4 s  = *(const float4*)&as_[k];
            float4 f, g;          // Wout first half / second half
            float a0, a1, a2, a3; // A'' values
            if (j < MM) {
                f = wr;
                g.x = -wi.x; g.y = -wi.y; g.z = -wi.z; g.w = -wi.w;
                a0 = wr.x * c.x - wi.x * s.x;
                a1 = wr.y * c.y - wi.y * s.y;
                a2 = wr.z * c.z - wi.z * s.z;
                a3 = wr.w * c.w - wi.w * s.w;
            } else {
                f = wi;
                g = wr;
                a0 = wi.x * c.x + wr.x * s.x;
                a1 = wi.y * c.y + wr.y * s.y;
                a2 = wi.z * c.z + wr.z * s.z;
                a3 = wi.w * c.w + wr.w * s.w;
            }
            // Hardtanh clamp (no-op on cos/sin, kept for fidelity)
            f.x = fminf(1.f, fmaxf(-1.f, f.x)); f.y = fminf(1.f, fmaxf(-1.f, f.y));
            f.z = fminf(1.f, fmaxf(-1.f, f.z)); f.w = fminf(1.f, fmaxf(-1.f, f.w));
            g.x = fminf(1.f, fmaxf(-1.f, g.x)); g.y = fminf(1.f, fmaxf(-1.f, g.y));
            g.z = fminf(1.f, fmaxf(-1.f, g.z)); g.w = fminf(1.f, fmaxf(-1.f, g.w));
            *(float4*)&Wout[(size_t)j * K2 + k]      = f;
            *(float4*)&Wout[(size_t)j * K2 + NN + k] = g;
            p.h[0] = __float2bfloat16(a0);
            p.h[1] = __float2bfloat16(a1);
            p.h[2] = __float2bfloat16(a2);
            p.h[3] = __float2bfloat16(a3);
        } else {
            p.h[0] = p.h[1] = p.h[2] = p.h[3] = __float2bfloat16(0.0f);
        }
        *(uint2*)&Abf[(size_t)j * NN + k] = p.u;
    } else {
        // ---- (b) transpose x [512 x 8192] fp32 -> Bxt bf16 [8192 x 512] ----
        const int tb = b - WPREP_BLOCKS;
        const int n0 = (tb & (XT_NB - 1)) * 32;   // 0..8160
        const int k0 = (tb >> 8) * 64;            // 0..448

        // load: 64 k-rows x 32 n-floats; thread = (row, 8-float chunk)
        const int row = tid >> 2;                  // 0..63
        const int c8  = (tid & 3) * 8;             // 0,8,16,24
        const float* src = &x[(size_t)(k0 + row) * CS + n0 + c8];
        const float4 v0 = *(const float4*)src;
        const float4 v1 = *(const float4*)(src + 4);
        float* tr = &tile[row * 33 + c8];
        tr[0] = v0.x; tr[1] = v0.y; tr[2] = v0.z; tr[3] = v0.w;
        tr[4] = v1.x; tr[5] = v1.y; tr[6] = v1.z; tr[7] = v1.w;
        __syncthreads();

        // store: thread = (n-row, k-octet); lanes 0..7 cover 128B contiguous
        const int oc = tid & 7;                    // k-octet 0..7
        const int nr = tid >> 3;                   // n 0..31
        union { __hip_bfloat16 h[8]; uint4 u; } q;
#pragma unroll
        for (int jj = 0; jj < 8; ++jj)
            q.h[jj] = __float2bfloat16(tile[(oc * 8 + jj) * 33 + nr]);
        *(uint4*)&Bxt[(size_t)(n0 + nr) * NN + k0 + oc * 8] = q.u;
    }
}

// -------------------------------------------------------------------------
// Kernel 2: GEMM  X[3680 x 8192] = A''[3680 x 512] * x[512 x 8192]
// Both operands K-contiguous bf16 (A: [m][k], B^T: [n][k]).
// 128x128 tile, BK=64, 256 threads (4 waves), each wave a 64x64 subtile
// (4x4 grid of 16x16x32 bf16 MFMA). global_load_lds width=16 staging.
// -------------------------------------------------------------------------
__device__ __forceinline__ void gload_lds16(const void* g, void* l) {
    __builtin_amdgcn_global_load_lds(
        (const __attribute__((address_space(1))) uint32_t*)g,
        (__attribute__((address_space(3))) uint32_t*)l,
        16, 0, 0);
}

__global__ __launch_bounds__(256) void czt_gemm(const __hip_bfloat16* __restrict__ Abf,
                                                const __hip_bfloat16* __restrict__ Bxt,
                                                float* __restrict__ Xout) {
    __shared__ __hip_bfloat16 As[128 * 64];   // [m in tile][k], stride 64
    __shared__ __hip_bfloat16 Bs[128 * 64];   // [n in tile][k], stride 64

    const int tid  = threadIdx.x;
    const int lane = tid & 63;
    const int w    = tid >> 6;        // wave 0..3
    const int quad = lane >> 4;       // 0..3
    const int r16  = lane & 15;

    const int mtile = blockIdx.y * 128;
    const int ntile = blockIdx.x * 128;
    const int wm = (w >> 1) * 64;     // wave row offset in tile
    const int wn = (w & 1) * 64;      // wave col offset in tile

    // Staging: wave w loads tile rows [w*32, w*32+32), 4 issues of
    // 8 rows x 64 elements (1 KiB per wave-issue).
    const int rstage = w * 32 + (lane >> 3);   // row within tile
    const int cstage = (lane & 7) * 8;         // k element offset (16 B)
    const __hip_bfloat16* Ag = Abf + (size_t)(mtile + rstage) * NN + cstage;
    const __hip_bfloat16* Bg = Bxt + (size_t)(ntile + rstage) * NN + cstage;

    floatx4 acc[4][4] = {};

#pragma unroll 1
    for (int kt = 0; kt < NN / 64; ++kt) {
        __syncthreads();   // previous iter's LDS reads done before overwrite
#pragma unroll
        for (int t = 0; t < 4; ++t) {
            gload_lds16(Ag + (size_t)(t * 8) * NN + kt * 64, &As[(w * 32 + t * 8) * 64]);
            gload_lds16(Bg + (size_t)(t * 8) * NN + kt * 64, &Bs[(w * 32 + t * 8) * 64]);
        }
        __syncthreads();   // vmcnt(0) drain -> tiles visible

#pragma unroll
        for (int ks = 0; ks < 2; ++ks) {
            bf16x8 af[4], bfr[4];
#pragma unroll
            for (int i = 0; i < 4; ++i) {
                af[i]  = *(const bf16x8*)&As[(wm + i * 16 + r16) * 64 + ks * 32 + quad * 8];
                bfr[i] = *(const bf16x8*)&Bs[(wn + i * 16 + r16) * 64 + ks * 32 + quad * 8];
            }
#pragma unroll
            for (int i = 0; i < 4; ++i)
#pragma unroll
                for (int jn = 0; jn < 4; ++jn)
                    acc[i][jn] = __builtin_amdgcn_mfma_f32_16x16x32_bf16(
                        af[i], bfr[jn], acc[i][jn], 0, 0, 0);
        }
    }

    // Epilogue: C/D layout col = lane&15, row = quad*4 + reg.
#pragma unroll
    for (int i = 0; i < 4; ++i) {
        const int rbase = mtile + wm + i * 16 + quad * 4;
#pragma unroll
        for (int rr = 0; rr < 4; ++rr) {
            const int rg = rbase + rr;
            if (rg < M2) {
#pragma unroll
                for (int jn = 0; jn < 4; ++jn) {
                    const int cg = ntile + wn + jn * 16 + r16;
                    Xout[(size_t)rg * CS + cg] = acc[i][jn][rr];
                }
            }
        }
    }
}

// -------------------------------------------------------------------------
extern "C" void kernel_launch(void* const* d_in, const int* in_sizes, int n_in,
                              void* d_out, int out_size, void* d_ws, size_t ws_size,
                              hipStream_t stream) {
    const float* x   = (const float*)d_in[0];   // [512, 32, 256]
    const float* Wr  = (const float*)d_in[1];   // [1840, 512]
    const float* Wi  = (const float*)d_in[2];   // [1840, 512]
    const float* ac  = (const float*)d_in[3];   // [512]
    const float* as_ = (const float*)d_in[4];   // [512]

    float* Wout = (float*)d_out;                       // [3680, 1024]
    float* Xout = (float*)d_out + (size_t)M2 * K2;     // [3680, 8192]

    __hip_bfloat16* Abf = (__hip_bfloat16*)d_ws;                                  // [3712, 512]
    __hip_bfloat16* Bxt = (__hip_bfloat16*)((char*)d_ws + (size_t)MPAD * NN * 2); // [8192, 512]

    czt_prep<<<dim3(WPREP_BLOCKS + XT_NB * XT_KB), dim3(256), 0, stream>>>(
        Wr, Wi, ac, as_, x, Wout, Abf, Bxt);
    czt_gemm<<<dim3(CS / 128, MPAD / 128), dim3(256), 0, stream>>>(Abf, Bxt, Xout);
}